// Round 18
// baseline (566.435 us; speedup 1.0000x reference)
//
#include <hip/hip_runtime.h>

// ---------------- problem constants ----------------
#define NB      8
#define SEQ     4096
#define DM      512
#define DFF     2048
#define NE      8
#define NTOK    32768            // NB*SEQ
#define NPB     2097152          // SEQ*DM elems per batch
#define MAXROWS 66560            // 520 * 128 >= 65536 + 8*127
#define MAXTILES 520             // 128-row tiles

// output layout (fp32 elements)
#define OUT_LB   16777216
#define OUT_TOPK 16777217
#define OUT_TASK 16842753

// ws byte offsets
#define WS_BSTATS   0            // double[512][2] (per xgate block)
#define WS_DMEAN    8192
#define WS_DRSTD    8256
#define WS_DCOLSUM  8320
#define WS_DTASK    8384         // double[8][8]
#define WS_HIST     8896
#define WS_CURSOR   8928
#define WS_SEGOFF   8960
#define WS_HDR_END  9216
#define WS_ROUTE_E  9216         // int2[32768]
#define WS_ROUTE_P  271360       // float2[32768]
#define WS_ATOK     533504       // int[66560]
#define WS_APROB    799744       // float[66560]
#define WS_TOKPOS   1065984      // int[32768*2]
#define WS_RAW      1328128      // double[32768][8]
#define WS_W1T      3425280      // ushort[8*2048*512]
#define WS_W2T      20202496     // ushort[8*512*2048]
#define WS_XB       36979712     // ushort[32768*512]
#define WS_Y        70534144     // ushort[66560*512]
#define WS_H        138691584    // ushort[tiles*128*2048]

typedef __attribute__((ext_vector_type(4))) float  f32x4;
typedef __attribute__((ext_vector_type(8))) __bf16 bf16x8;
typedef __attribute__((ext_vector_type(8))) short  s16x8;

__device__ __forceinline__ unsigned short f2bf(float f) {
    unsigned int u = __builtin_bit_cast(unsigned int, f);
    u += 0x7FFFu + ((u >> 16) & 1u);
    return (unsigned short)(u >> 16);
}
__device__ __forceinline__ float bf2f(unsigned short b) {
    unsigned int u = ((unsigned int)b) << 16;
    return __builtin_bit_cast(float, u);
}
__device__ __forceinline__ unsigned int pkbf(float a, float b) {
    unsigned int r;
    asm("v_cvt_pk_bf16_f32 %0, %1, %2" : "=v"(r) : "v"(a), "v"(b));
    return r;
}
// silu via hw reciprocal (v_rcp_f32, ~2^-14 rel err -- invisible after bf16 round)
__device__ __forceinline__ float silu_f(float v) {
    return v * __builtin_amdgcn_rcpf(1.0f + __expf(-v));
}

#define GLDS16(g, l)                                                              \
    __builtin_amdgcn_global_load_lds(                                             \
        (const __attribute__((address_space(1))) unsigned int*)(const void*)(g),  \
        (__attribute__((address_space(3))) unsigned int*)(void*)(l), 16, 0, 0)

// ---------------- weight transpose + bf16 convert ----------------
__global__ void k_transpose_bf16(const float* __restrict__ in,
                                 unsigned short* __restrict__ outT,
                                 int R, int C) {
    __shared__ float tile[32][33];
    int e = blockIdx.z;
    const float* src = in + (size_t)e * R * C;
    unsigned short* dst = outT + (size_t)e * R * C;
    int tx = threadIdx.x & 31, ty = threadIdx.x >> 5;
    int c0 = blockIdx.x * 32, r0 = blockIdx.y * 32;
#pragma unroll
    for (int i = 0; i < 4; i++) {
        int r = r0 + ty + i * 8;
        tile[ty + i * 8][tx] = src[(size_t)r * C + c0 + tx];
    }
    __syncthreads();
#pragma unroll
    for (int i = 0; i < 4; i++) {
        int rr = c0 + ty + i * 8;
        dst[(size_t)rr * R + r0 + tx] = f2bf(tile[tx][ty + i * 8]);
    }
}

// ---------------- fused: gate raw logits (fp64) + x->bf16 + batch stats ----------------
// 4 THREADS per token (128 dims each). Quarter regions of gate_w in LDS padded
// (+8 floats) so the 4 concurrent quarter-addresses hit banks {0,8,16,24}.
#define GQPAD 1032               // 128 rows * 8 + 8 pad floats
__global__ void __launch_bounds__(256) k_xgate(const float* __restrict__ x,
                                               const float* __restrict__ gw,
                                               unsigned short* __restrict__ xb,
                                               double* __restrict__ bstats,
                                               double* __restrict__ raw) {
    __shared__ float gws[4 * GQPAD];   // ~16.5 KB
    int t = threadIdx.x;
#pragma unroll
    for (int i = 0; i < 16; i++) {
        int idx = i * 256 + t;               // 0..4095 over gw rows 0..511
        int row = idx >> 3, e = idx & 7;
        gws[(row >> 7) * GQPAD + (row & 127) * 8 + e] = gw[idx];
    }
    __syncthreads();

    int token = blockIdx.x * 64 + (t >> 2);
    int q = t & 3;                            // dim quarter
    const float4* xp = (const float4*)(x + (size_t)token * DM + q * 128);
    unsigned short* xbp = xb + (size_t)token * DM + q * 128;
    const float* gq = &gws[q * GQPAD];

    double acc[8] = {0, 0, 0, 0, 0, 0, 0, 0};
    double s = 0.0, ss = 0.0;
#pragma unroll 4
    for (int i = 0; i < 32; i += 2) {
        float4 v0 = xp[i];
        float4 v1 = xp[i + 1];
        {
            double dx = v0.x, dy = v0.y, dz = v0.z, dw = v0.w;
            const float* g = &gq[i * 32];
#pragma unroll
            for (int e = 0; e < 8; e++)
                acc[e] += dx * (double)g[e] + dy * (double)g[8 + e]
                        + dz * (double)g[16 + e] + dw * (double)g[24 + e];
            s  += dx + dy + dz + dw;
            ss += dx * dx + dy * dy + dz * dz + dw * dw;
        }
        {
            double dx = v1.x, dy = v1.y, dz = v1.z, dw = v1.w;
            const float* g = &gq[(i + 1) * 32];
#pragma unroll
            for (int e = 0; e < 8; e++)
                acc[e] += dx * (double)g[e] + dy * (double)g[8 + e]
                        + dz * (double)g[16 + e] + dw * (double)g[24 + e];
            s  += dx + dy + dz + dw;
            ss += dx * dx + dy * dy + dz * dz + dw * dw;
        }
        s16x8 o = {(short)f2bf(v0.x), (short)f2bf(v0.y), (short)f2bf(v0.z), (short)f2bf(v0.w),
                   (short)f2bf(v1.x), (short)f2bf(v1.y), (short)f2bf(v1.z), (short)f2bf(v1.w)};
        *(s16x8*)(xbp + i * 4) = o;
    }

    // combine the 4 dim-quarters (lanes q=0..3 within each 4-lane group)
#pragma unroll
    for (int e = 0; e < 8; e++) {
        acc[e] += __shfl_xor(acc[e], 1);
        acc[e] += __shfl_xor(acc[e], 2);
    }
    if (q == 0) {
#pragma unroll
        for (int e = 0; e < 8; e++) raw[(size_t)token * 8 + e] = acc[e];
    }

    // block stats reduction (fp64)
    for (int o = 32; o; o >>= 1) { s += __shfl_down(s, o); ss += __shfl_down(ss, o); }
    __shared__ double as_[4], ass_[4];
    int w = t >> 6;
    if ((t & 63) == 0) { as_[w] = s; ass_[w] = ss; }
    __syncthreads();
    if (t == 0) {
        s  = as_[0] + as_[1] + as_[2] + as_[3];
        ss = ass_[0] + ass_[1] + ass_[2] + ass_[3];
        bstats[blockIdx.x * 2]     = s;
        bstats[blockIdx.x * 2 + 1] = ss;
    }
}

// ---------------- finalize mean/rstd, gate colsum, task terms ----------------
__global__ void k_finalize(const double* __restrict__ bstats,
                           double* __restrict__ dmean, double* __restrict__ drstd,
                           double* __restrict__ dcolsum, double* __restrict__ dtask,
                           const float* __restrict__ gw, const float* __restrict__ gb,
                           const float* __restrict__ temb, const int* __restrict__ task_id,
                           float* __restrict__ out_task) {
    int t = threadIdx.x;
    if (t < 8) {
        double s = 0.0, ss = 0.0;
        for (int i = 0; i < 64; i++) {          // 64 xgate blocks per batch
            s  += bstats[(t * 64 + i) * 2];
            ss += bstats[(t * 64 + i) * 2 + 1];
        }
        double N = (double)NPB;
        double m = s / N;
        double var = ss / N - m * m;
        dmean[t] = m;
        drstd[t] = 1.0 / sqrt(var + 1e-5);
    }
    __shared__ double colp[32][8];
    {
        int e = t & 7, g = t >> 3;
        double a = 0.0;
        for (int r = g * 16; r < g * 16 + 16; r++) a += (double)gw[r * 8 + e];
        colp[g][e] = a;
    }
    __syncthreads();
    if (t < 8) {
        double a = 0.0;
        for (int g = 0; g < 32; g++) a += colp[g][t];
        dcolsum[t] = a;
    }
    if (t < 64) {
        int b2 = t >> 3, e = t & 7;
        int tid = task_id[b2];
        double a = (double)gb[e];
        for (int d = 0; d < 64; d++)
            a += (double)temb[tid * 64 + d] * (double)gw[(512 + d) * 8 + e];
        dtask[t] = a;
    }
    if (t < 8) out_task[t] = (float)task_id[t];
}

// ---------------- top-2 from raw logits ----------------
__global__ void __launch_bounds__(256) k_topk(const double* __restrict__ raw,
                                              const double* __restrict__ dmean,
                                              const double* __restrict__ drstd,
                                              const double* __restrict__ dcolsum,
                                              const double* __restrict__ dtask,
                                              int* __restrict__ hist,
                                              int2* __restrict__ route_e,
                                              float2* __restrict__ route_p,
                                              float* __restrict__ out_topk) {
    __shared__ int lh[8];
    int t = threadIdx.x;
    if (t < 8) lh[t] = 0;
    __syncthreads();
    int token = blockIdx.x * 256 + t;
    int b = token >> 12;
    double m = dmean[b], rs = drstd[b];
    double lg[8];
#pragma unroll
    for (int e = 0; e < 8; e++)
        lg[e] = rs * (raw[(size_t)token * 8 + e] - m * dcolsum[e]) + dtask[b * 8 + e];
    int i0 = 0;
#pragma unroll
    for (int e = 1; e < 8; e++) if (lg[e] > lg[i0]) i0 = e;
    int i1 = (i0 == 0) ? 1 : 0;
#pragma unroll
    for (int e = 0; e < 8; e++) if (e != i0 && lg[e] > lg[i1]) i1 = e;
    double d = exp(lg[i1] - lg[i0]);
    double p0 = 1.0 / (1.0 + d);
    double p1 = d / (1.0 + d);
    out_topk[token * 2]     = (float)i0;
    out_topk[token * 2 + 1] = (float)i1;
    atomicAdd(&lh[i0], 1);
    atomicAdd(&lh[i1], 1);
    route_e[token] = make_int2(i0, i1);
    route_p[token] = make_float2((float)p0, (float)p1);
    __syncthreads();
    if (t < 8) atomicAdd(&hist[t], lh[t]);
}

// ---------------- segment offsets (128-padded) + lb_loss ----------------
__global__ void k_offsets_lb(const int* __restrict__ hist, int* __restrict__ seg_off,
                             float* __restrict__ out_lb) {
    if (threadIdx.x == 0) {
        int off = 0;
        double ssd = 0.0;
        for (int e = 0; e < 8; e++) {
            seg_off[e] = off;
            off += (hist[e] + 127) & ~127;
            double d = (double)hist[e] - 8192.0;
            ssd += d * d;
        }
        seg_off[8] = off;
        double stdv = sqrt(ssd / 7.0);
        double m = 8192.0 + 1e-6;
        double r = stdv / m;
        *out_lb = (float)(r * r);
    }
}

// ---------------- scatter: LDS-aggregated two-level + inverse map ----------------
__global__ void __launch_bounds__(256) k_scatter(const int2* __restrict__ route_e,
                                                 const float2* __restrict__ route_p,
                                                 const int* __restrict__ seg_off,
                                                 int* __restrict__ cursor,
                                                 int* __restrict__ atok,
                                                 float* __restrict__ aprob,
                                                 int* __restrict__ tokpos) {
    __shared__ int lcount[8];
    __shared__ int lbase[8];
    int t = threadIdx.x;
    if (t < 8) lcount[t] = 0;
    __syncthreads();
    int tok = blockIdx.x * 256 + t;
    int2 e = route_e[tok];
    float2 p = route_p[tok];
    int p0 = atomicAdd(&lcount[e.x], 1);
    int p1 = atomicAdd(&lcount[e.y], 1);
    __syncthreads();
    if (t < 8) lbase[t] = atomicAdd(&cursor[t], lcount[t]);
    __syncthreads();
    int a0 = seg_off[e.x] + lbase[e.x] + p0;
    atok[a0] = tok; aprob[a0] = p.x;
    int a1 = seg_off[e.y] + lbase[e.y] + p1;
    atok[a1] = tok; aprob[a1] = p.y;
    tokpos[tok * 2]     = a0;
    tokpos[tok * 2 + 1] = a1;
}

// ---------------- GEMM1: m97-style BK=32 single-buffer (16 KB LDS, high occupancy) ----------------
// Per K-step: 4x global_load_lds(16B) -> __syncthreads -> 8x ds_read_b128 + 16 MFMA
// -> __syncthreads. Barrier drain is hidden by 4-5 co-resident blocks/CU (m97/m114).
// mfma(bfv, af): lane's 4 acc elems = 4 consecutive OUTPUT COLUMNS.
__global__ void __launch_bounds__(256) k_gemm1(const unsigned short* __restrict__ xb,
                                               const unsigned short* __restrict__ w1t,
                                               const float* __restrict__ b1,
                                               const int* __restrict__ atok,
                                               const int* __restrict__ seg_off,
                                               unsigned short* __restrict__ H,
                                               int t0) {
    int nwg = (int)gridDim.x;                       // tpc*16, multiple of 8
    int bid = (int)blockIdx.x;
    int wg = (bid & 7) * (nwg >> 3) + (bid >> 3);   // XCD-chunked logical id
    int xt = wg >> 4, y = wg & 15;                  // NY = 16
    int r0 = (t0 + xt) * 128;
    if (r0 >= seg_off[8]) return;
    int e = 0;
    while (seg_off[e + 1] <= r0) e++;
    int f0 = y * 128;

    int tid = threadIdx.x;
    int w = tid >> 6, l = tid & 63;
    int wr = w >> 1, wc = w & 1, lr = l & 15, q = l >> 4;

    __shared__ __align__(16) unsigned short As[128 * 32];
    __shared__ __align__(16) unsigned short Bs[128 * 32];

    // staging map: issue j covers rows j*64 + w*16 + (l>>2); lane covers 8 elems
    // at col (l&3)*8 of the 32-elem row. LDS dest = wave-uniform base + lane*16.
    int rsub = l >> 2;                 // 0..15
    int koff = (l & 3) * 8;            // 0,8,16,24
    int row0 = w * 16 + rsub;
    int row1 = row0 + 64;
    int tok0 = atok[r0 + row0]; if (tok0 < 0) tok0 = 0;
    int tok1 = atok[r0 + row1]; if (tok1 < 0) tok1 = 0;
    const unsigned short* a0 = xb + (size_t)tok0 * DM + koff;
    const unsigned short* a1 = xb + (size_t)tok1 * DM + koff;
    const unsigned short* b0 = w1t + ((size_t)e * DFF + f0 + row0) * DM + koff;
    const unsigned short* b1p = w1t + ((size_t)e * DFF + f0 + row1) * DM + koff;
    unsigned short* ad0 = &As[(w * 16) * 32];
    unsigned short* ad1 = &As[(w * 16 + 64) * 32];
    unsigned short* bd0 = &Bs[(w * 16) * 32];
    unsigned short* bd1 = &Bs[(w * 16 + 64) * 32];

    f32x4 acc[4][4] = {};

    for (int kt = 0; kt < DM / 32; ++kt) {          // 16 K-steps
        int kk = kt * 32;
        GLDS16(a0 + kk, ad0);
        GLDS16(a1 + kk, ad1);
        GLDS16(b0 + kk, bd0);
        GLDS16(b1p + kk, bd1);
        __syncthreads();
        bf16x8 af[4], bfv[4];
#pragma unroll
        for (int m = 0; m < 4; m++)
            af[m] = *(const bf16x8*)&As[(wr * 64 + m * 16 + lr) * 32 + q * 8];
#pragma unroll
        for (int n = 0; n < 4; n++)
            bfv[n] = *(const bf16x8*)&Bs[(wc * 64 + n * 16 + lr) * 32 + q * 8];
#pragma unroll
        for (int m = 0; m < 4; m++)
#pragma unroll
            for (int n = 0; n < 4; n++)
                acc[m][n] = __builtin_amdgcn_mfma_f32_16x16x32_bf16(bfv[n], af[m], acc[m][n], 0, 0, 0);
        __syncthreads();
    }

    // epilogue: acc[m][n][j] = H[r = wr*64+m*16+lr][f = f0 + wc*64 + n*16 + q*4 + j]
    const float* b1e = b1 + e * DFF + f0;
#pragma unroll
    for (int m = 0; m < 4; m++) {
        int r = wr * 64 + m * 16 + lr;
        unsigned short* hrow = H + ((size_t)xt * 128 + r) * DFF + f0;
#pragma unroll
        for (int n = 0; n < 4; n++) {
            int fc = wc * 64 + n * 16 + q * 4;
            float4 bias = *(const float4*)(b1e + fc);
            float v0 = silu_f(acc[m][n][0] + bias.x);
            float v1 = silu_f(acc[m][n][1] + bias.y);
            float v2 = silu_f(acc[m][n][2] + bias.z);
            float v3 = silu_f(acc[m][n][3] + bias.w);
            *(uint2*)(hrow + fc) = make_uint2(pkbf(v0, v1), pkbf(v2, v3));
        }
    }
}

// ---------------- GEMM2: Y[aidx] = H[chunk] @ w2[e]  (K=2048, 2-phase dbuf, counted vmcnt) ----------------
__global__ void __launch_bounds__(256) k_gemm2(const unsigned short* __restrict__ H,
                                               const unsigned short* __restrict__ w2t,
                                               const int* __restrict__ seg_off,
                                               unsigned short* __restrict__ Y,
                                               int t0) {
    int nwg = (int)gridDim.x;                       // tpc*4, tpc even -> %8==0
    int bid = (int)blockIdx.x;
    int wg = (bid & 7) * (nwg >> 3) + (bid >> 3);
    int xt = wg >> 2, y = wg & 3;                   // NY = 4
    int r0 = (t0 + xt) * 128;
    if (r0 >= seg_off[8]) return;
    int e = 0;
    while (seg_off[e + 1] <= r0) e++;
    int d0 = y * 128;

    int tid = threadIdx.x;
    int w = tid >> 6, l = tid & 63;
    int c = l & 7;

    __shared__ __align__(16) unsigned short As[2][128 * 64];
    __shared__ __align__(16) unsigned short Bs[2][128 * 64];

    const unsigned short* asrc[4];
    const unsigned short* bsrc[4];
    unsigned short*       adst[4];
    unsigned short*       bdst[4];
#pragma unroll
    for (int j = 0; j < 4; j++) {
        int R = w * 32 + j * 8 + (l >> 3);
        int cs = c ^ (R & 7);
        asrc[j] = H + ((size_t)xt * 128 + R) * DFF + cs * 8;
        bsrc[j] = w2t + ((size_t)e * DM + d0 + R) * DFF + cs * 8;
        adst[j] = &As[0][(size_t)(w * 32 + j * 8) * 64];
        bdst[j] = &Bs[0][(size_t)(w * 32 + j * 8) * 64];
    }

    f32x4 acc[4][4] = {};
    int wr = w >> 1, wc = w & 1, lr = l & 15, q = l >> 4;

    // prologue
#pragma unroll
    for (int j = 0; j < 4; j++) { GLDS16(asrc[j], adst[j]); GLDS16(bsrc[j], bdst[j]); }

    int cur = 0;
    for (int it = 0; it < DFF / 64; ++it) {         // 32 K-steps
        if (it + 1 < DFF / 64) {
            int kn = (it + 1) * 64;
            int off = (cur ^ 1) * 128 * 64;
#pragma unroll
            for (int j = 0; j < 4; j++) {
                GLDS16(asrc[j] + kn, adst[j] + off);
                GLDS16(bsrc[j] + kn, bdst[j] + off);
            }
            asm volatile("s_waitcnt vmcnt(8)" ::: "memory");
        } else {
            asm volatile("s_waitcnt vmcnt(0)" ::: "memory");
        }
        __builtin_amdgcn_s_barrier();
        __builtin_amdgcn_sched_barrier(0);
        __builtin_amdgcn_s_setprio(1);
        const unsigned short* Ab = &As[cur][0];
        const unsigned short* Bb = &Bs[cur][0];
#pragma unroll
        for (int h = 0; h < 2; h++) {
            bf16x8 af[4], bfv[4];
#pragma unroll
            for (int m = 0; m < 4; m++) {
                int R = wr * 64 + m * 16 + lr;
                af[m] = *(const bf16x8*)&Ab[R * 64 + (((h << 2) + q) ^ (R & 7)) * 8];
            }
#pragma unroll
            for (int n = 0; n < 4; n++) {
                int R = wc * 64 + n * 16 + lr;
                bfv[n] = *(const bf16x8*)&Bb[R * 64 + (((h << 2) + q) ^ (R & 7)) * 8];
            }
#pragma unroll
            for (int m = 0; m < 4; m++)
#pragma unroll
                for (int n = 0; n < 4; n++)
                    acc[m][n] = __builtin_amdgcn_mfma_f32_16x16x32_bf16(bfv[n], af[m], acc[m][n], 0, 0, 0);
        }
        __builtin_amdgcn_s_setprio(0);
        __builtin_amdgcn_sched_barrier(0);
        asm volatile("" ::: "memory");
        __builtin_amdgcn_s_barrier();
        cur ^= 1;
    }

    // epilogue: acc[m][n][j] = Y[r = wr*64+m*16+lr][d = d0 + wc*64 + n*16 + q*4 + j]
#pragma unroll
    for (int m = 0; m < 4; m++) {
        int r = wr * 64 + m * 16 + lr;
        unsigned short* yrow = Y + (size_t)(r0 + r) * DM + d0;
#pragma unroll
        for (int n = 0; n < 4; n++) {
            int dc = wc * 64 + n * 16 + q * 4;
            *(uint2*)(yrow + dc) = make_uint2(pkbf(acc[m][n][0], acc[m][n][1]),
                                              pkbf(acc[m][n][2], acc[m][n][3]));
        }
    }
}

// ---------------- combine: out[t] = p0*(Y[a0]+b2[e0]) + p1*(Y[a1]+b2[e1]) ----------------
__global__ void __launch_bounds__(256) k_combine(const unsigned short* __restrict__ Y,
                                                 const float* __restrict__ b2,
                                                 const int* __restrict__ tokpos,
                                                 const int2* __restrict__ route_e,
                                                 const float2* __restrict__ route_p,
                                                 float* __restrict__ out) {
    int gt = blockIdx.x * 256 + threadIdx.x;
    int token = gt >> 6;
    int cbase = (gt & 63) * 8;
    int2 e = route_e[token];
    float2 p = route_p[token];
    int a0 = tokpos[token * 2], a1 = tokpos[token * 2 + 1];
    s16x8 y0 = *(const s16x8*)(Y + (size_t)a0 * DM + cbase);
    s16x8 y1 = *(const s16x8*)(Y + (size_t)a1 * DM + cbase);
    const float4* bb0 = (const float4*)(b2 + e.x * DM + cbase);
    const float4* bb1 = (const float4*)(b2 + e.y * DM + cbase);
    float4 b00 = bb0[0], b01 = bb0[1];
    float4 b10 = bb1[0], b11 = bb1[1];
    float r[8];
    r[0] = p.x * (bf2f((unsigned short)y0[0]) + b00.x) + p.y * (bf2f((unsigned short)y1[0]) + b10.x);
    r[1] = p.x * (bf2f((unsigned short)y0[1]) + b00.y) + p.y * (bf2f((unsigned short)y1[1]) + b10.y);
    r[2] = p.x * (bf2f((unsigned short)y0[2]) + b00.z) + p.y * (bf2f((unsigned short)y1[2]) + b10.z);
    r[3] = p.x * (bf2f((unsigned short)y0[3]) + b00.w) + p.y * (bf2f((unsigned short)y1[3]) + b10.w);
    r[4] = p.x * (bf2f((unsigned short)y0[4]) + b01.x) + p.y * (bf2f((unsigned short)y1[4]) + b11.x);
    r[5] = p.x * (bf2f((unsigned short)y0[5]) + b01.y) + p.y * (bf2f((unsigned short)y1[5]) + b11.y);
    r[6] = p.x * (bf2f((unsigned short)y0[6]) + b01.z) + p.y * (bf2f((unsigned short)y1[6]) + b11.z);
    r[7] = p.x * (bf2f((unsigned short)y0[7]) + b01.w) + p.y * (bf2f((unsigned short)y1[7]) + b11.w);
    float* op = out + (size_t)token * DM + cbase;
    *(float4*)op       = make_float4(r[0], r[1], r[2], r[3]);
    *(float4*)(op + 4) = make_float4(r[4], r[5], r[6], r[7]);
}

// ---------------- launch ----------------
extern "C" void kernel_launch(void* const* d_in, const int* in_sizes, int n_in,
                              void* d_out, int out_size, void* d_ws, size_t ws_size,
                              hipStream_t stream) {
    const float* x       = (const float*)d_in[0];
    const int*   task_id = (const int*)d_in[1];
    const float* w1      = (const float*)d_in[2];
    const float* b1      = (const float*)d_in[3];
    const float* w2      = (const float*)d_in[4];
    const float* b2      = (const float*)d_in[5];
    const float* temb    = (const float*)d_in[6];
    const float* gw      = (const float*)d_in[7];
    const float* gb      = (const float*)d_in[8];
    float* out = (float*)d_out;

    char* ws = (char*)d_ws;
    double* bstats   = (double*)(ws + WS_BSTATS);
    double* dmean    = (double*)(ws + WS_DMEAN);
    double* drstd    = (double*)(ws + WS_DRSTD);
    double* dcolsum  = (double*)(ws + WS_DCOLSUM);
    double* dtask    = (double*)(ws + WS_DTASK);
    int*    hist     = (int*)(ws + WS_HIST);
    int*    cursor   = (int*)(ws + WS_CURSOR);
    int*    seg_off  = (int*)(ws + WS_SEGOFF);
    int2*   route_e  = (int2*)(ws + WS_ROUTE_E);
    float2* route_p  = (float2*)(ws + WS_ROUTE_P);
    int*    atok     = (int*)(ws + WS_ATOK);
    float*  aprob    = (float*)(ws + WS_APROB);
    int*    tokpos   = (int*)(ws + WS_TOKPOS);
    double* raw      = (double*)(ws + WS_RAW);
    unsigned short* w1t = (unsigned short*)(ws + WS_W1T);
    unsigned short* w2t = (unsigned short*)(ws + WS_W2T);
    unsigned short* xb  = (unsigned short*)(ws + WS_XB);
    unsigned short* Y   = (unsigned short*)(ws + WS_Y);
    unsigned short* H   = (unsigned short*)(ws + WS_H);

    // 128-row tiles per chunk. TPC=128 quantizes gemm2's grid to the 512-block
    // LDS-limited round; final chunk absorbs a small tail (straggler backfill).
    int space_tiles = (int)((ws_size - (size_t)WS_H) / (size_t)(128 * DFF * 2));
    int TPC = space_tiles;
    if (TPC > 128) TPC = 128;
    TPC &= ~1;
    if (TPC < 2) TPC = 2;

    hipMemsetAsync(ws, 0, WS_HDR_END, stream);
    hipMemsetAsync(ws + WS_ATOK, 0xFF, (size_t)MAXROWS * sizeof(int), stream);

    k_transpose_bf16<<<dim3(DFF / 32, DM / 32, NE), 256, 0, stream>>>(w1, w1t, DM, DFF);
    k_transpose_bf16<<<dim3(DM / 32, DFF / 32, NE), 256, 0, stream>>>(w2, w2t, DFF, DM);

    // fused gate-raw + x->bf16 + stats (single pass over x, 4 threads/token)
    k_xgate<<<NTOK / 64, 256, 0, stream>>>(x, gw, xb, bstats, raw);
    k_finalize<<<1, 256, 0, stream>>>(bstats, dmean, drstd, dcolsum, dtask,
                                      gw, gb, temb, task_id, out + OUT_TASK);
    k_topk<<<NTOK / 256, 256, 0, stream>>>(raw, dmean, drstd, dcolsum, dtask,
                                           hist, route_e, route_p, out + OUT_TOPK);
    k_offsets_lb<<<1, 64, 0, stream>>>(hist, seg_off, out + OUT_LB);
    k_scatter<<<NTOK / 256, 256, 0, stream>>>(route_e, route_p, seg_off, cursor,
                                              atok, aprob, tokpos);

    int t0 = 0;
    while (t0 < MAXTILES) {
        int rem = MAXTILES - t0;
        int tpc_c = TPC;
        if (rem > TPC && rem <= TPC + 16 && rem <= space_tiles) tpc_c = rem;
        else if (rem <= TPC) tpc_c = rem;
        tpc_c &= ~1;
        if (tpc_c < 2) tpc_c = 2;
        k_gemm1<<<tpc_c * 16, 256, 0, stream>>>(xb, w1t, b1, atok, seg_off, H, t0);
        k_gemm2<<<tpc_c * 4, 256, 0, stream>>>(H, w2t, seg_off, Y, t0);
        t0 += tpc_c;
    }
    k_combine<<<NTOK / 4, 256, 0, stream>>>(Y, b2, tokpos, route_e, route_p, out);
}

// Round 19
// 529.387 us; speedup vs baseline: 1.0700x; 1.0700x over previous
//
#include <hip/hip_runtime.h>

// ---------------- problem constants ----------------
#define NB      8
#define SEQ     4096
#define DM      512
#define DFF     2048
#define NE      8
#define NTOK    32768            // NB*SEQ
#define NPB     2097152          // SEQ*DM elems per batch
#define MAXROWS 66560            // 520 * 128 >= 65536 + 8*127
#define MAXTILES 520             // 128-row tiles

// output layout (fp32 elements)
#define OUT_LB   16777216
#define OUT_TOPK 16777217
#define OUT_TASK 16842753

// ws byte offsets
#define WS_BSTATS   0            // double[512][2] (per xgate block)
#define WS_DMEAN    8192
#define WS_DRSTD    8256
#define WS_DCOLSUM  8320
#define WS_DTASK    8384         // double[8][8]
#define WS_HIST     8896
#define WS_CURSOR   8928
#define WS_SEGOFF   8960
#define WS_HDR_END  9216
#define WS_ROUTE_E  9216         // int2[32768]
#define WS_ROUTE_P  271360       // float2[32768]
#define WS_ATOK     533504       // int[66560]
#define WS_APROB    799744       // float[66560]
#define WS_TOKPOS   1065984      // int[32768*2]
#define WS_RAW      1328128      // double[32768][8]
#define WS_W1T      3425280      // ushort[8*2048*512]
#define WS_W2T      20202496     // ushort[8*512*2048]
#define WS_XB       36979712     // ushort[32768*512]
#define WS_Y        70534144     // ushort[66560*512]
#define WS_H        138691584    // ushort[tiles*128*2048]

typedef __attribute__((ext_vector_type(4))) float  f32x4;
typedef __attribute__((ext_vector_type(8))) __bf16 bf16x8;
typedef __attribute__((ext_vector_type(8))) short  s16x8;

__device__ __forceinline__ unsigned short f2bf(float f) {
    unsigned int u = __builtin_bit_cast(unsigned int, f);
    u += 0x7FFFu + ((u >> 16) & 1u);
    return (unsigned short)(u >> 16);
}
__device__ __forceinline__ float bf2f(unsigned short b) {
    unsigned int u = ((unsigned int)b) << 16;
    return __builtin_bit_cast(float, u);
}
__device__ __forceinline__ unsigned int pkbf(float a, float b) {
    unsigned int r;
    asm("v_cvt_pk_bf16_f32 %0, %1, %2" : "=v"(r) : "v"(a), "v"(b));
    return r;
}
// silu via hw reciprocal (v_rcp_f32, ~2^-14 rel err -- invisible after bf16 round)
__device__ __forceinline__ float silu_f(float v) {
    return v * __builtin_amdgcn_rcpf(1.0f + __expf(-v));
}

#define GLDS16(g, l)                                                              \
    __builtin_amdgcn_global_load_lds(                                             \
        (const __attribute__((address_space(1))) unsigned int*)(const void*)(g),  \
        (__attribute__((address_space(3))) unsigned int*)(void*)(l), 16, 0, 0)

// ---------------- weight transpose + bf16 convert ----------------
__global__ void k_transpose_bf16(const float* __restrict__ in,
                                 unsigned short* __restrict__ outT,
                                 int R, int C) {
    __shared__ float tile[32][33];
    int e = blockIdx.z;
    const float* src = in + (size_t)e * R * C;
    unsigned short* dst = outT + (size_t)e * R * C;
    int tx = threadIdx.x & 31, ty = threadIdx.x >> 5;
    int c0 = blockIdx.x * 32, r0 = blockIdx.y * 32;
#pragma unroll
    for (int i = 0; i < 4; i++) {
        int r = r0 + ty + i * 8;
        tile[ty + i * 8][tx] = src[(size_t)r * C + c0 + tx];
    }
    __syncthreads();
#pragma unroll
    for (int i = 0; i < 4; i++) {
        int rr = c0 + ty + i * 8;
        dst[(size_t)rr * R + r0 + tx] = f2bf(tile[tx][ty + i * 8]);
    }
}

// ---------------- fused: gate raw logits (fp64) + x->bf16 + batch stats ----------------
// 4 THREADS per token (128 dims each). Quarter regions of gate_w in LDS padded
// (+8 floats) so the 4 concurrent quarter-addresses hit banks {0,8,16,24}.
#define GQPAD 1032               // 128 rows * 8 + 8 pad floats
__global__ void __launch_bounds__(256) k_xgate(const float* __restrict__ x,
                                               const float* __restrict__ gw,
                                               unsigned short* __restrict__ xb,
                                               double* __restrict__ bstats,
                                               double* __restrict__ raw) {
    __shared__ float gws[4 * GQPAD];   // ~16.5 KB
    int t = threadIdx.x;
#pragma unroll
    for (int i = 0; i < 16; i++) {
        int idx = i * 256 + t;               // 0..4095 over gw rows 0..511
        int row = idx >> 3, e = idx & 7;
        gws[(row >> 7) * GQPAD + (row & 127) * 8 + e] = gw[idx];
    }
    __syncthreads();

    int token = blockIdx.x * 64 + (t >> 2);
    int q = t & 3;                            // dim quarter
    const float4* xp = (const float4*)(x + (size_t)token * DM + q * 128);
    unsigned short* xbp = xb + (size_t)token * DM + q * 128;
    const float* gq = &gws[q * GQPAD];

    double acc[8] = {0, 0, 0, 0, 0, 0, 0, 0};
    double s = 0.0, ss = 0.0;
#pragma unroll 4
    for (int i = 0; i < 32; i += 2) {
        float4 v0 = xp[i];
        float4 v1 = xp[i + 1];
        {
            double dx = v0.x, dy = v0.y, dz = v0.z, dw = v0.w;
            const float* g = &gq[i * 32];
#pragma unroll
            for (int e = 0; e < 8; e++)
                acc[e] += dx * (double)g[e] + dy * (double)g[8 + e]
                        + dz * (double)g[16 + e] + dw * (double)g[24 + e];
            s  += dx + dy + dz + dw;
            ss += dx * dx + dy * dy + dz * dz + dw * dw;
        }
        {
            double dx = v1.x, dy = v1.y, dz = v1.z, dw = v1.w;
            const float* g = &gq[(i + 1) * 32];
#pragma unroll
            for (int e = 0; e < 8; e++)
                acc[e] += dx * (double)g[e] + dy * (double)g[8 + e]
                        + dz * (double)g[16 + e] + dw * (double)g[24 + e];
            s  += dx + dy + dz + dw;
            ss += dx * dx + dy * dy + dz * dz + dw * dw;
        }
        s16x8 o = {(short)f2bf(v0.x), (short)f2bf(v0.y), (short)f2bf(v0.z), (short)f2bf(v0.w),
                   (short)f2bf(v1.x), (short)f2bf(v1.y), (short)f2bf(v1.z), (short)f2bf(v1.w)};
        *(s16x8*)(xbp + i * 4) = o;
    }

    // combine the 4 dim-quarters (lanes q=0..3 within each 4-lane group)
#pragma unroll
    for (int e = 0; e < 8; e++) {
        acc[e] += __shfl_xor(acc[e], 1);
        acc[e] += __shfl_xor(acc[e], 2);
    }
    if (q == 0) {
#pragma unroll
        for (int e = 0; e < 8; e++) raw[(size_t)token * 8 + e] = acc[e];
    }

    // block stats reduction (fp64)
    for (int o = 32; o; o >>= 1) { s += __shfl_down(s, o); ss += __shfl_down(ss, o); }
    __shared__ double as_[4], ass_[4];
    int w = t >> 6;
    if ((t & 63) == 0) { as_[w] = s; ass_[w] = ss; }
    __syncthreads();
    if (t == 0) {
        s  = as_[0] + as_[1] + as_[2] + as_[3];
        ss = ass_[0] + ass_[1] + ass_[2] + ass_[3];
        bstats[blockIdx.x * 2]     = s;
        bstats[blockIdx.x * 2 + 1] = ss;
    }
}

// ---------------- finalize mean/rstd, gate colsum, task terms ----------------
__global__ void k_finalize(const double* __restrict__ bstats,
                           double* __restrict__ dmean, double* __restrict__ drstd,
                           double* __restrict__ dcolsum, double* __restrict__ dtask,
                           const float* __restrict__ gw, const float* __restrict__ gb,
                           const float* __restrict__ temb, const int* __restrict__ task_id,
                           float* __restrict__ out_task) {
    int t = threadIdx.x;
    if (t < 8) {
        double s = 0.0, ss = 0.0;
        for (int i = 0; i < 64; i++) {          // 64 xgate blocks per batch
            s  += bstats[(t * 64 + i) * 2];
            ss += bstats[(t * 64 + i) * 2 + 1];
        }
        double N = (double)NPB;
        double m = s / N;
        double var = ss / N - m * m;
        dmean[t] = m;
        drstd[t] = 1.0 / sqrt(var + 1e-5);
    }
    __shared__ double colp[32][8];
    {
        int e = t & 7, g = t >> 3;
        double a = 0.0;
        for (int r = g * 16; r < g * 16 + 16; r++) a += (double)gw[r * 8 + e];
        colp[g][e] = a;
    }
    __syncthreads();
    if (t < 8) {
        double a = 0.0;
        for (int g = 0; g < 32; g++) a += colp[g][t];
        dcolsum[t] = a;
    }
    if (t < 64) {
        int b2 = t >> 3, e = t & 7;
        int tid = task_id[b2];
        double a = (double)gb[e];
        for (int d = 0; d < 64; d++)
            a += (double)temb[tid * 64 + d] * (double)gw[(512 + d) * 8 + e];
        dtask[t] = a;
    }
    if (t < 8) out_task[t] = (float)task_id[t];
}

// ---------------- top-2 from raw logits ----------------
__global__ void __launch_bounds__(256) k_topk(const double* __restrict__ raw,
                                              const double* __restrict__ dmean,
                                              const double* __restrict__ drstd,
                                              const double* __restrict__ dcolsum,
                                              const double* __restrict__ dtask,
                                              int* __restrict__ hist,
                                              int2* __restrict__ route_e,
                                              float2* __restrict__ route_p,
                                              float* __restrict__ out_topk) {
    __shared__ int lh[8];
    int t = threadIdx.x;
    if (t < 8) lh[t] = 0;
    __syncthreads();
    int token = blockIdx.x * 256 + t;
    int b = token >> 12;
    double m = dmean[b], rs = drstd[b];
    double lg[8];
#pragma unroll
    for (int e = 0; e < 8; e++)
        lg[e] = rs * (raw[(size_t)token * 8 + e] - m * dcolsum[e]) + dtask[b * 8 + e];
    int i0 = 0;
#pragma unroll
    for (int e = 1; e < 8; e++) if (lg[e] > lg[i0]) i0 = e;
    int i1 = (i0 == 0) ? 1 : 0;
#pragma unroll
    for (int e = 0; e < 8; e++) if (e != i0 && lg[e] > lg[i1]) i1 = e;
    double d = exp(lg[i1] - lg[i0]);
    double p0 = 1.0 / (1.0 + d);
    double p1 = d / (1.0 + d);
    out_topk[token * 2]     = (float)i0;
    out_topk[token * 2 + 1] = (float)i1;
    atomicAdd(&lh[i0], 1);
    atomicAdd(&lh[i1], 1);
    route_e[token] = make_int2(i0, i1);
    route_p[token] = make_float2((float)p0, (float)p1);
    __syncthreads();
    if (t < 8) atomicAdd(&hist[t], lh[t]);
}

// ---------------- segment offsets (128-padded) + lb_loss ----------------
__global__ void k_offsets_lb(const int* __restrict__ hist, int* __restrict__ seg_off,
                             float* __restrict__ out_lb) {
    if (threadIdx.x == 0) {
        int off = 0;
        double ssd = 0.0;
        for (int e = 0; e < 8; e++) {
            seg_off[e] = off;
            off += (hist[e] + 127) & ~127;
            double d = (double)hist[e] - 8192.0;
            ssd += d * d;
        }
        seg_off[8] = off;
        double stdv = sqrt(ssd / 7.0);
        double m = 8192.0 + 1e-6;
        double r = stdv / m;
        *out_lb = (float)(r * r);
    }
}

// ---------------- scatter: LDS-aggregated two-level + inverse map ----------------
__global__ void __launch_bounds__(256) k_scatter(const int2* __restrict__ route_e,
                                                 const float2* __restrict__ route_p,
                                                 const int* __restrict__ seg_off,
                                                 int* __restrict__ cursor,
                                                 int* __restrict__ atok,
                                                 float* __restrict__ aprob,
                                                 int* __restrict__ tokpos) {
    __shared__ int lcount[8];
    __shared__ int lbase[8];
    int t = threadIdx.x;
    if (t < 8) lcount[t] = 0;
    __syncthreads();
    int tok = blockIdx.x * 256 + t;
    int2 e = route_e[tok];
    float2 p = route_p[tok];
    int p0 = atomicAdd(&lcount[e.x], 1);
    int p1 = atomicAdd(&lcount[e.y], 1);
    __syncthreads();
    if (t < 8) lbase[t] = atomicAdd(&cursor[t], lcount[t]);
    __syncthreads();
    int a0 = seg_off[e.x] + lbase[e.x] + p0;
    atok[a0] = tok; aprob[a0] = p.x;
    int a1 = seg_off[e.y] + lbase[e.y] + p1;
    atok[a1] = tok; aprob[a1] = p.y;
    tokpos[tok * 2]     = a0;
    tokpos[tok * 2 + 1] = a1;
}

// ============ MFMA GEMMs: proven 2-phase double-buffered pipeline ============
// LDS: As[2]/Bs[2], XOR-swizzled [128][64] tiles staged via global_load_lds(16B).
// Per iter: issue next-tile stage -> s_waitcnt vmcnt(8) (counted; prefetch stays
// in flight) -> s_barrier -> ds_read+MFMA (setprio 1) -> s_barrier -> flip.
// mfma(bfv, af): lane's 4 acc elems = 4 consecutive OUTPUT COLUMNS.

// ---------------- GEMM1: 2 f-tiles per block (fill amortized; A pointers shared) ----------------
__global__ void __launch_bounds__(256) k_gemm1(const unsigned short* __restrict__ xb,
                                               const unsigned short* __restrict__ w1t,
                                               const float* __restrict__ b1,
                                               const int* __restrict__ atok,
                                               const int* __restrict__ seg_off,
                                               unsigned short* __restrict__ H,
                                               int t0) {
    int nwg = (int)gridDim.x;                       // tpc*8, multiple of 8
    int bid = (int)blockIdx.x;
    int wg = (bid & 7) * (nwg >> 3) + (bid >> 3);   // XCD-chunked logical id
    int xt = wg >> 3, fgrp = wg & 7;                // 8 f-groups of 2 tiles
    int r0 = (t0 + xt) * 128;
    if (r0 >= seg_off[8]) return;
    int e = 0;
    while (seg_off[e + 1] <= r0) e++;

    int tid = threadIdx.x;
    int w = tid >> 6, l = tid & 63;
    int c = l & 7;
    int wr = w >> 1, wc = w & 1, lr = l & 15, q = l >> 4;

    __shared__ __align__(16) unsigned short As[2][128 * 64];
    __shared__ __align__(16) unsigned short Bs[2][128 * 64];

    const unsigned short* asrc[4];
    const unsigned short* bsrc[4];                  // ft=0 pointers; ft=1 = +128*DM
    unsigned short*       adst[4];
    unsigned short*       bdst[4];
#pragma unroll
    for (int j = 0; j < 4; j++) {
        int R = w * 32 + j * 8 + (l >> 3);
        int cs = c ^ (R & 7);
        int tok = atok[r0 + R]; if (tok < 0) tok = 0;
        asrc[j] = xb + (size_t)tok * DM + cs * 8;
        bsrc[j] = w1t + ((size_t)e * DFF + fgrp * 256 + R) * DM + cs * 8;
        adst[j] = &As[0][(size_t)(w * 32 + j * 8) * 64];
        bdst[j] = &Bs[0][(size_t)(w * 32 + j * 8) * 64];
    }

    // prologue: stage ft0's kt0 into buffer 0
#pragma unroll
    for (int j = 0; j < 4; j++) { GLDS16(asrc[j], adst[j]); GLDS16(bsrc[j], bdst[j]); }

#pragma unroll
    for (int ft = 0; ft < 2; ++ft) {
        const int bofs = ft * 128 * DM;             // f-tile offset in w1t
        f32x4 acc[4][4] = {};
        int cur = 0;
#pragma unroll
        for (int it = 0; it < 8; ++it) {            // K = 512, BK = 64
            if (it < 7) {
                int kn = (it + 1) * 64;
                int off = (cur ^ 1) * 128 * 64;
#pragma unroll
                for (int j = 0; j < 4; j++) {
                    GLDS16(asrc[j] + kn, adst[j] + off);
                    GLDS16(bsrc[j] + bofs + kn, bdst[j] + off);
                }
                asm volatile("s_waitcnt vmcnt(8)" ::: "memory");
            } else if (ft == 0) {
                // stage ft1's kt0 into the free buffer (= buf0: cur==1 here).
                // vmcnt(8) still exactly drains the current buffer's 8 loads.
                int off = (cur ^ 1) * 128 * 64;
#pragma unroll
                for (int j = 0; j < 4; j++) {
                    GLDS16(asrc[j], adst[j] + off);
                    GLDS16(bsrc[j] + 128 * DM, bdst[j] + off);
                }
                asm volatile("s_waitcnt vmcnt(8)" ::: "memory");
            } else {
                asm volatile("s_waitcnt vmcnt(0)" ::: "memory");
            }
            __builtin_amdgcn_s_barrier();
            __builtin_amdgcn_sched_barrier(0);
            __builtin_amdgcn_s_setprio(1);
            const unsigned short* Ab = &As[cur][0];
            const unsigned short* Bb = &Bs[cur][0];
#pragma unroll
            for (int h = 0; h < 2; h++) {
                bf16x8 af[4], bfv[4];
#pragma unroll
                for (int m = 0; m < 4; m++) {
                    int R = wr * 64 + m * 16 + lr;
                    af[m] = *(const bf16x8*)&Ab[R * 64 + (((h << 2) + q) ^ (R & 7)) * 8];
                }
#pragma unroll
                for (int n = 0; n < 4; n++) {
                    int R = wc * 64 + n * 16 + lr;
                    bfv[n] = *(const bf16x8*)&Bb[R * 64 + (((h << 2) + q) ^ (R & 7)) * 8];
                }
#pragma unroll
                for (int m = 0; m < 4; m++)
#pragma unroll
                    for (int n = 0; n < 4; n++)
                        acc[m][n] = __builtin_amdgcn_mfma_f32_16x16x32_bf16(bfv[n], af[m], acc[m][n], 0, 0, 0);
            }
            __builtin_amdgcn_s_setprio(0);
            __builtin_amdgcn_sched_barrier(0);
            asm volatile("" ::: "memory");
            __builtin_amdgcn_s_barrier();
            cur ^= 1;
        }

        // epilogue for this f-tile (ft1's kt0 loads stay in flight; they are
        // drained by ft1's first vmcnt(8), which also retires these stores)
        int f0 = (fgrp * 2 + ft) * 128;
        const float* b1e = b1 + e * DFF + f0;
#pragma unroll
        for (int m = 0; m < 4; m++) {
            int r = wr * 64 + m * 16 + lr;
            unsigned short* hrow = H + ((size_t)xt * 128 + r) * DFF + f0;
#pragma unroll
            for (int n = 0; n < 4; n++) {
                int fc = wc * 64 + n * 16 + q * 4;
                float4 bias = *(const float4*)(b1e + fc);
                float v0 = silu_f(acc[m][n][0] + bias.x);
                float v1 = silu_f(acc[m][n][1] + bias.y);
                float v2 = silu_f(acc[m][n][2] + bias.z);
                float v3 = silu_f(acc[m][n][3] + bias.w);
                *(uint2*)(hrow + fc) = make_uint2(pkbf(v0, v1), pkbf(v2, v3));
            }
        }
    }
}

// ---------------- GEMM2: Y[aidx] = H[chunk] @ w2[e]  (K=2048, plain bf16 stores) ----------------
__global__ void __launch_bounds__(256) k_gemm2(const unsigned short* __restrict__ H,
                                               const unsigned short* __restrict__ w2t,
                                               const int* __restrict__ seg_off,
                                               unsigned short* __restrict__ Y,
                                               int t0) {
    int nwg = (int)gridDim.x;                       // tpc*4, tpc even -> %8==0
    int bid = (int)blockIdx.x;
    int wg = (bid & 7) * (nwg >> 3) + (bid >> 3);
    int xt = wg >> 2, y = wg & 3;                   // NY = 4
    int r0 = (t0 + xt) * 128;
    if (r0 >= seg_off[8]) return;
    int e = 0;
    while (seg_off[e + 1] <= r0) e++;
    int d0 = y * 128;

    int tid = threadIdx.x;
    int w = tid >> 6, l = tid & 63;
    int c = l & 7;

    __shared__ __align__(16) unsigned short As[2][128 * 64];
    __shared__ __align__(16) unsigned short Bs[2][128 * 64];

    const unsigned short* asrc[4];
    const unsigned short* bsrc[4];
    unsigned short*       adst[4];
    unsigned short*       bdst[4];
#pragma unroll
    for (int j = 0; j < 4; j++) {
        int R = w * 32 + j * 8 + (l >> 3);
        int cs = c ^ (R & 7);
        asrc[j] = H + ((size_t)xt * 128 + R) * DFF + cs * 8;
        bsrc[j] = w2t + ((size_t)e * DM + d0 + R) * DFF + cs * 8;
        adst[j] = &As[0][(size_t)(w * 32 + j * 8) * 64];
        bdst[j] = &Bs[0][(size_t)(w * 32 + j * 8) * 64];
    }

    f32x4 acc[4][4] = {};
    int wr = w >> 1, wc = w & 1, lr = l & 15, q = l >> 4;

    // prologue
#pragma unroll
    for (int j = 0; j < 4; j++) { GLDS16(asrc[j], adst[j]); GLDS16(bsrc[j], bdst[j]); }

    int cur = 0;
    for (int it = 0; it < DFF / 64; ++it) {         // 32 K-steps
        if (it + 1 < DFF / 64) {
            int kn = (it + 1) * 64;
            int off = (cur ^ 1) * 128 * 64;
#pragma unroll
            for (int j = 0; j < 4; j++) {
                GLDS16(asrc[j] + kn, adst[j] + off);
                GLDS16(bsrc[j] + kn, bdst[j] + off);
            }
            asm volatile("s_waitcnt vmcnt(8)" ::: "memory");
        } else {
            asm volatile("s_waitcnt vmcnt(0)" ::: "memory");
        }
        __builtin_amdgcn_s_barrier();
        __builtin_amdgcn_sched_barrier(0);
        __builtin_amdgcn_s_setprio(1);
        const unsigned short* Ab = &As[cur][0];
        const unsigned short* Bb = &Bs[cur][0];
#pragma unroll
        for (int h = 0; h < 2; h++) {
            bf16x8 af[4], bfv[4];
#pragma unroll
            for (int m = 0; m < 4; m++) {
                int R = wr * 64 + m * 16 + lr;
                af[m] = *(const bf16x8*)&Ab[R * 64 + (((h << 2) + q) ^ (R & 7)) * 8];
            }
#pragma unroll
            for (int n = 0; n < 4; n++) {
                int R = wc * 64 + n * 16 + lr;
                bfv[n] = *(const bf16x8*)&Bb[R * 64 + (((h << 2) + q) ^ (R & 7)) * 8];
            }
#pragma unroll
            for (int m = 0; m < 4; m++)
#pragma unroll
                for (int n = 0; n < 4; n++)
                    acc[m][n] = __builtin_amdgcn_mfma_f32_16x16x32_bf16(bfv[n], af[m], acc[m][n], 0, 0, 0);
        }
        __builtin_amdgcn_s_setprio(0);
        __builtin_amdgcn_sched_barrier(0);
        asm volatile("" ::: "memory");
        __builtin_amdgcn_s_barrier();
        cur ^= 1;
    }

    // epilogue: acc[m][n][j] = Y[r = wr*64+m*16+lr][d = d0 + wc*64 + n*16 + q*4 + j]
#pragma unroll
    for (int m = 0; m < 4; m++) {
        int r = wr * 64 + m * 16 + lr;
        unsigned short* yrow = Y + (size_t)(r0 + r) * DM + d0;
#pragma unroll
        for (int n = 0; n < 4; n++) {
            int dc = wc * 64 + n * 16 + q * 4;
            *(uint2*)(yrow + dc) = make_uint2(pkbf(acc[m][n][0], acc[m][n][1]),
                                              pkbf(acc[m][n][2], acc[m][n][3]));
        }
    }
}

// ---------------- combine: out[t] = p0*(Y[a0]+b2[e0]) + p1*(Y[a1]+b2[e1]) ----------------
__global__ void __launch_bounds__(256) k_combine(const unsigned short* __restrict__ Y,
                                                 const float* __restrict__ b2,
                                                 const int* __restrict__ tokpos,
                                                 const int2* __restrict__ route_e,
                                                 const float2* __restrict__ route_p,
                                                 float* __restrict__ out) {
    int gt = blockIdx.x * 256 + threadIdx.x;
    int token = gt >> 6;
    int cbase = (gt & 63) * 8;
    int2 e = route_e[token];
    float2 p = route_p[token];
    int a0 = tokpos[token * 2], a1 = tokpos[token * 2 + 1];
    s16x8 y0 = *(const s16x8*)(Y + (size_t)a0 * DM + cbase);
    s16x8 y1 = *(const s16x8*)(Y + (size_t)a1 * DM + cbase);
    const float4* bb0 = (const float4*)(b2 + e.x * DM + cbase);
    const float4* bb1 = (const float4*)(b2 + e.y * DM + cbase);
    float4 b00 = bb0[0], b01 = bb0[1];
    float4 b10 = bb1[0], b11 = bb1[1];
    float r[8];
    r[0] = p.x * (bf2f((unsigned short)y0[0]) + b00.x) + p.y * (bf2f((unsigned short)y1[0]) + b10.x);
    r[1] = p.x * (bf2f((unsigned short)y0[1]) + b00.y) + p.y * (bf2f((unsigned short)y1[1]) + b10.y);
    r[2] = p.x * (bf2f((unsigned short)y0[2]) + b00.z) + p.y * (bf2f((unsigned short)y1[2]) + b10.z);
    r[3] = p.x * (bf2f((unsigned short)y0[3]) + b00.w) + p.y * (bf2f((unsigned short)y1[3]) + b10.w);
    r[4] = p.x * (bf2f((unsigned short)y0[4]) + b01.x) + p.y * (bf2f((unsigned short)y1[4]) + b11.x);
    r[5] = p.x * (bf2f((unsigned short)y0[5]) + b01.y) + p.y * (bf2f((unsigned short)y1[5]) + b11.y);
    r[6] = p.x * (bf2f((unsigned short)y0[6]) + b01.z) + p.y * (bf2f((unsigned short)y1[6]) + b11.z);
    r[7] = p.x * (bf2f((unsigned short)y0[7]) + b01.w) + p.y * (bf2f((unsigned short)y1[7]) + b11.w);
    float* op = out + (size_t)token * DM + cbase;
    *(float4*)op       = make_float4(r[0], r[1], r[2], r[3]);
    *(float4*)(op + 4) = make_float4(r[4], r[5], r[6], r[7]);
}

// ---------------- launch ----------------
extern "C" void kernel_launch(void* const* d_in, const int* in_sizes, int n_in,
                              void* d_out, int out_size, void* d_ws, size_t ws_size,
                              hipStream_t stream) {
    const float* x       = (const float*)d_in[0];
    const int*   task_id = (const int*)d_in[1];
    const float* w1      = (const float*)d_in[2];
    const float* b1      = (const float*)d_in[3];
    const float* w2      = (const float*)d_in[4];
    const float* b2      = (const float*)d_in[5];
    const float* temb    = (const float*)d_in[6];
    const float* gw      = (const float*)d_in[7];
    const float* gb      = (const float*)d_in[8];
    float* out = (float*)d_out;

    char* ws = (char*)d_ws;
    double* bstats   = (double*)(ws + WS_BSTATS);
    double* dmean    = (double*)(ws + WS_DMEAN);
    double* drstd    = (double*)(ws + WS_DRSTD);
    double* dcolsum  = (double*)(ws + WS_DCOLSUM);
    double* dtask    = (double*)(ws + WS_DTASK);
    int*    hist     = (int*)(ws + WS_HIST);
    int*    cursor   = (int*)(ws + WS_CURSOR);
    int*    seg_off  = (int*)(ws + WS_SEGOFF);
    int2*   route_e  = (int2*)(ws + WS_ROUTE_E);
    float2* route_p  = (float2*)(ws + WS_ROUTE_P);
    int*    atok     = (int*)(ws + WS_ATOK);
    float*  aprob    = (float*)(ws + WS_APROB);
    int*    tokpos   = (int*)(ws + WS_TOKPOS);
    double* raw      = (double*)(ws + WS_RAW);
    unsigned short* w1t = (unsigned short*)(ws + WS_W1T);
    unsigned short* w2t = (unsigned short*)(ws + WS_W2T);
    unsigned short* xb  = (unsigned short*)(ws + WS_XB);
    unsigned short* Y   = (unsigned short*)(ws + WS_Y);
    unsigned short* H   = (unsigned short*)(ws + WS_H);

    // 128-row tiles per chunk. Base TPC=128 quantizes to the 512-block
    // concurrency limit (2 blocks/CU x 256 CU at 64 KB LDS). The final chunk
    // ABSORBS the residual tail (<= TPC+16 tiles) so no extra near-empty
    // dispatch pair: its 64/32 straggler blocks backfill as round-1 blocks
    // retire, instead of costing two fresh ~full-round latencies.
    int space_tiles = (int)((ws_size - (size_t)WS_H) / (size_t)(128 * DFF * 2));
    int TPC = space_tiles;
    if (TPC > 128) TPC = 128;
    TPC &= ~1;
    if (TPC < 2) TPC = 2;

    hipMemsetAsync(ws, 0, WS_HDR_END, stream);
    hipMemsetAsync(ws + WS_ATOK, 0xFF, (size_t)MAXROWS * sizeof(int), stream);

    k_transpose_bf16<<<dim3(DFF / 32, DM / 32, NE), 256, 0, stream>>>(w1, w1t, DM, DFF);
    k_transpose_bf16<<<dim3(DM / 32, DFF / 32, NE), 256, 0, stream>>>(w2, w2t, DFF, DM);

    // fused gate-raw + x->bf16 + stats (single pass over x, 4 threads/token)
    k_xgate<<<NTOK / 64, 256, 0, stream>>>(x, gw, xb, bstats, raw);
    k_finalize<<<1, 256, 0, stream>>>(bstats, dmean, drstd, dcolsum, dtask,
                                      gw, gb, temb, task_id, out + OUT_TASK);
    k_topk<<<NTOK / 256, 256, 0, stream>>>(raw, dmean, drstd, dcolsum, dtask,
                                           hist, route_e, route_p, out + OUT_TOPK);
    k_offsets_lb<<<1, 64, 0, stream>>>(hist, seg_off, out + OUT_LB);
    k_scatter<<<NTOK / 256, 256, 0, stream>>>(route_e, route_p, seg_off, cursor,
                                              atok, aprob, tokpos);

    int t0 = 0;
    while (t0 < MAXTILES) {
        int rem = MAXTILES - t0;
        int tpc_c = TPC;
        // absorb a small tail into this (final) chunk if H space allows
        if (rem > TPC && rem <= TPC + 16 && rem <= space_tiles) tpc_c = rem;
        else if (rem <= TPC) tpc_c = rem;
        tpc_c &= ~1;
        if (tpc_c < 2) tpc_c = 2;
        k_gemm1<<<tpc_c * 8, 256, 0, stream>>>(xb, w1t, b1, atok, seg_off, H, t0);
        k_gemm2<<<tpc_c * 4, 256, 0, stream>>>(H, w2t, seg_off, Y, t0);
        t0 += tpc_c;
    }
    k_combine<<<NTOK / 4, 256, 0, stream>>>(Y, b2, tokpos, route_e, route_p, out);
}